// Round 3
// baseline (315.172 us; speedup 1.0000x reference)
//
#include <hip/hip_runtime.h>
#include <hip/hip_bf16.h>
#include <math.h>

// Problem constants (B=4, T=2048, C=1024, H=16, D=64)
#define SEQ   2048
#define NTOK  8192          // B*T
#define EMB   1024
#define QKVF  3072

typedef __bf16 bf16;
typedef __bf16 bf16x8 __attribute__((ext_vector_type(8)));
typedef __bf16 bf16x4 __attribute__((ext_vector_type(4)));
typedef float  f32x4  __attribute__((ext_vector_type(4)));

__device__ __forceinline__ void gload_lds16(const bf16* g, bf16* l) {
    __builtin_amdgcn_global_load_lds(
        (const __attribute__((address_space(1))) unsigned int*)g,
        (__attribute__((address_space(3))) unsigned int*)l,
        16, 0, 0);
}

// ---------------- fp32 -> bf16 conversion (vectorized x4) ----------------
__global__ __launch_bounds__(256) void cvt_f32_bf16(const float* __restrict__ in,
                                                    bf16* __restrict__ out, int n) {
    int i = (blockIdx.x * 256 + threadIdx.x) * 4;
    if (i >= n) return;
    float4 f = *reinterpret_cast<const float4*>(in + i);
    bf16x4 o;
    o[0] = (bf16)f.x; o[1] = (bf16)f.y; o[2] = (bf16)f.z; o[3] = (bf16)f.w;
    *reinterpret_cast<bf16x4*>(out + i) = o;
}

// ---------------- 8-wave pipelined bt-GEMM: C[M,N] = A[M,K]*B[N,K]^T + bias ----
// BM=256, BN=NF*64 (NF=4 -> 256, NF=2 -> 128), BK=64. 512 threads = 8 waves (2x4).
// Per-wave output: 128 x (NF*16). Double-buffered swizzled LDS, 4 phases/K-tile,
// counted vmcnt (T4), setprio around MFMA (T5), XOR swizzle (T2).
template <int NF, bool BF16OUT>
__global__ __launch_bounds__(512, 2) void gemm_bt8(const bf16* __restrict__ A,
                                                   const bf16* __restrict__ Bm,
                                                   const float* __restrict__ bias,
                                                   void* __restrict__ out,
                                                   int M, int N, int K) {
    constexpr int NBR = NF / 2;          // B staging rounds per K-panel
    constexpr int WN  = NBR + 2;         // counted-vmcnt immediate
    __shared__ bf16 As[2][256 * 64];             // [buf][row*64 + chunk*8], swizzled
    __shared__ bf16 Bs[2][2][NF * 64 * 32];      // [buf][kk][row*32 + chunk*8], swizzled

    const int nbx = N / (NF * 64);
    const int nwg = nbx * (M >> 8);
    const int q8  = nwg >> 3;
    const int swz = ((int)blockIdx.x & 7) * q8 + ((int)blockIdx.x >> 3);
    const int bx  = swz % nbx;
    const int by  = swz / nbx;

    const int tid  = threadIdx.x;
    const int lane = tid & 63;
    const int wid  = tid >> 6;
    const int wr   = wid >> 2, wc = wid & 3;
    const int lr   = lane & 15, hi = lane >> 4;
    const size_t brow = (size_t)by * 256;
    const size_t bcol = (size_t)bx * (NF * 64);

    const f32x4 fzero = {0.f, 0.f, 0.f, 0.f};
    f32x4 acc[8][NF];
#pragma unroll
    for (int m = 0; m < 8; ++m)
#pragma unroll
        for (int n = 0; n < NF; ++n) acc[m][n] = fzero;

// --- staging macros: LDS dest linear (gload_lds requirement), GLOBAL src pre-swizzled
#define STAGE_A_ROUND(b, kt, r) do {                                            \
    const int row_ = (r) * 64 + (tid >> 3);                                     \
    const int cg_  = (tid & 7) ^ (row_ & 7);                                    \
    gload_lds16(A + (brow + row_) * (size_t)K + (size_t)(kt) * 64 + cg_ * 8,    \
                &As[b][(r) * 4096 + tid * 8]);                                  \
} while (0)
#define STAGE_B_ROUND(b, kt, kkp, rr) do {                                      \
    const int row_ = (rr) * 128 + (tid >> 2);                                   \
    const int cg_  = (tid & 3) ^ (row_ & 3);                                    \
    gload_lds16(Bm + (bcol + row_) * (size_t)K + (size_t)(kt) * 64 +            \
                    (kkp) * 32 + cg_ * 8,                                       \
                &Bs[b][kkp][(rr) * 4096 + tid * 8]);                            \
} while (0)
// g1 = A rounds {0,2} + B panel0 ; g2 = B panel1 ; g3 = A rounds {1,3}
#define ISSUE_G1(b, kt) do { STAGE_A_ROUND(b, kt, 0); STAGE_A_ROUND(b, kt, 2);  \
    for (int rr_ = 0; rr_ < NBR; ++rr_) STAGE_B_ROUND(b, kt, 0, rr_); } while (0)
#define ISSUE_G2(b, kt) do {                                                    \
    for (int rr_ = 0; rr_ < NBR; ++rr_) STAGE_B_ROUND(b, kt, 1, rr_); } while (0)
#define ISSUE_G3(b, kt) do { STAGE_A_ROUND(b, kt, 1); STAGE_A_ROUND(b, kt, 3); } while (0)

// --- fragment reads (swizzled)
#define READ_A(b, mh, kk, dst) do {                                             \
    _Pragma("unroll")                                                           \
    for (int i_ = 0; i_ < 4; ++i_) {                                            \
        const int row_ = wr * 128 + (mh) * 64 + i_ * 16 + lr;                   \
        dst[i_] = *reinterpret_cast<const bf16x8*>(                             \
            (const char*)&As[b][0] + row_ * 128 +                               \
            (((kk) * 64 + hi * 16) ^ ((row_ & 7) << 4)));                       \
    }                                                                           \
} while (0)
#define READ_B(b, kk, dst) do {                                                 \
    _Pragma("unroll")                                                           \
    for (int n_ = 0; n_ < NF; ++n_) {                                           \
        const int row_ = wc * (NF * 16) + n_ * 16 + lr;                         \
        dst[n_] = *reinterpret_cast<const bf16x8*>(                             \
            (const char*)&Bs[b][kk][0] + row_ * 64 +                            \
            ((hi * 16) ^ ((row_ & 3) << 4)));                                   \
    }                                                                           \
} while (0)
#define DO_MFMA(mh, afr, bfr) do {                                              \
    __builtin_amdgcn_s_setprio(1);                                              \
    _Pragma("unroll")                                                           \
    for (int i_ = 0; i_ < 4; ++i_)                                              \
        _Pragma("unroll")                                                       \
        for (int n_ = 0; n_ < NF; ++n_)                                         \
            acc[(mh) * 4 + i_][n_] = __builtin_amdgcn_mfma_f32_16x16x32_bf16(   \
                afr[i_], bfr[n_], acc[(mh) * 4 + i_][n_], 0, 0, 0);             \
    __builtin_amdgcn_s_setprio(0);                                              \
} while (0)

    const int NT = K >> 6;

    // prologue: stage tile 0 into buf 0, in group order g1,g2,g3
    ISSUE_G1(0, 0);
    ISSUE_G2(0, 0);
    ISSUE_G3(0, 0);
    asm volatile("s_waitcnt vmcnt(%0)" :: "i"(WN) : "memory");  // g1(0) done
    __builtin_amdgcn_s_barrier();

    bf16x8 af[4], bk0[NF], bk1[NF];

    for (int kt = 0; kt < NT; ++kt) {
        const int  b    = kt & 1;
        const int  nb   = b ^ 1;
        const bool last = (kt == NT - 1);

        // ---- P1: quad (mh0, kk0) ----
        if (!last) ISSUE_G1(nb, kt + 1);
        READ_A(b, 0, 0, af);
        READ_B(b, 0, bk0);
        if (last) asm volatile("s_waitcnt vmcnt(0)" ::: "memory");
        else      asm volatile("s_waitcnt vmcnt(%0)" :: "i"(WN) : "memory"); // g2,g3(kt) done
        __builtin_amdgcn_s_barrier();
        DO_MFMA(0, af, bk0);
        __builtin_amdgcn_s_barrier();

        // ---- P2: quad (mh0, kk1) ----
        if (!last) ISSUE_G2(nb, kt + 1);
        READ_A(b, 0, 1, af);
        READ_B(b, 1, bk1);
        __builtin_amdgcn_s_barrier();
        DO_MFMA(0, af, bk1);
        __builtin_amdgcn_s_barrier();

        // ---- P3: quad (mh1, kk1) ----
        if (!last) ISSUE_G3(nb, kt + 1);
        READ_A(b, 1, 1, af);
        __builtin_amdgcn_s_barrier();
        DO_MFMA(1, af, bk1);
        __builtin_amdgcn_s_barrier();

        // ---- P4: quad (mh1, kk0) ----
        READ_A(b, 1, 0, af);
        if (!last) asm volatile("s_waitcnt vmcnt(%0)" :: "i"(WN) : "memory"); // g1(kt+1) done
        __builtin_amdgcn_s_barrier();
        DO_MFMA(1, af, bk0);
        __builtin_amdgcn_s_barrier();
    }

    // ---- epilogue: bias + store
#pragma unroll
    for (int mf = 0; mf < 8; ++mf)
#pragma unroll
        for (int n = 0; n < NF; ++n)
#pragma unroll
            for (int r = 0; r < 4; ++r) {
                const size_t row = brow + wr * 128 + mf * 16 + hi * 4 + r;
                const size_t col = bcol + wc * (NF * 16) + n * 16 + lr;
                const float v = acc[mf][n][r] + bias[col];
                if (BF16OUT)
                    ((bf16*)out)[row * (size_t)N + col] = (bf16)v;
                else
                    ((float*)out)[row * (size_t)N + col] = v;
            }
#undef STAGE_A_ROUND
#undef STAGE_B_ROUND
#undef ISSUE_G1
#undef ISSUE_G2
#undef ISSUE_G3
#undef READ_A
#undef READ_B
#undef DO_MFMA
}

// ---------------- causal flash attention v2 (unchanged) ----------------
__global__ __launch_bounds__(256) void attn_kernel(const bf16* __restrict__ qkv,
                                                   bf16* __restrict__ o) {
    const int bid = blockIdx.x;
    const int qt  = 15 - (bid >> 6);     // 16 q-tiles; longest first
    const int bh  = bid & 63;
    const int h   = bh & 15;
    const int b   = bh >> 4;
    const int qbase = qt * 128;

    const int tid  = threadIdx.x;
    const int wv   = tid >> 6;
    const int lane = tid & 63;
    const int lr   = lane & 15, hi = lane >> 4;

    __shared__ bf16 Ks[64 * 64];          // K tile [k][d], XOR-swizzled rows
    __shared__ bf16 Vt[64 * 64];          // V^T tile [d][k], XOR-swizzled rows
    __shared__ bf16 Pl[4 * 32 * 64];      // per-wave P [q][k], XOR-swizzled rows

    char* Ksb = (char*)Ks;
    char* Vtb = (char*)Vt;
    char* Pb  = (char*)(Pl + wv * 2048);

    const size_t tokbase = (size_t)b * SEQ;

    bf16x8 aq[2][2];
#pragma unroll
    for (int qf = 0; qf < 2; ++qf) {
        const bf16* qg = qkv + (tokbase + qbase + wv * 32 + qf * 16 + lr) * (size_t)QKVF
                         + h * 64;
#pragma unroll
        for (int kk = 0; kk < 2; ++kk)
            aq[qf][kk] = *reinterpret_cast<const bf16x8*>(qg + kk * 32 + hi * 8);
    }

    const f32x4 fzero = {0.f, 0.f, 0.f, 0.f};
    f32x4 oacc[2][4];
#pragma unroll
    for (int qf = 0; qf < 2; ++qf)
#pragma unroll
        for (int n = 0; n < 4; ++n) oacc[qf][n] = fzero;
    float m_r[2] = {-__builtin_inff(), -__builtin_inff()};
    float l_r[2] = {0.f, 0.f};

    const int nkv = qt * 2 + 2;
    const float SC = 0.125f * 1.44269504f; // 1/sqrt(64) * log2(e)

    const int vk0 = tid >> 3;
    const int vc  = tid & 7;

    for (int kt = 0; kt < nkv; ++kt) {
        const size_t kvrow = tokbase + (size_t)kt * 64;
        __syncthreads();

#pragma unroll
        for (int j = 0; j < 2; ++j) {
            const int kr = wv * 16 + j * 8 + (lane >> 3);
            const int cg = (lane & 7) ^ ((lane >> 3) & 7);
            gload_lds16(qkv + (kvrow + kr) * (size_t)QKVF + EMB + h * 64 + cg * 8,
                        &Ks[(wv * 16 + j * 8) * 64 + lane * 8]);
        }

        {
            bf16x8 v0 = *reinterpret_cast<const bf16x8*>(
                qkv + (kvrow + vk0) * (size_t)QKVF + 2 * EMB + h * 64 + vc * 8);
            bf16x8 v1 = *reinterpret_cast<const bf16x8*>(
                qkv + (kvrow + vk0 + 32) * (size_t)QKVF + 2 * EMB + h * 64 + vc * 8);
#pragma unroll
            for (int jj = 0; jj < 8; ++jj) {
                const int d = vc * 8 + jj;
                char* row = Vtb + d * 128;
                *(bf16*)(row + ((vk0 * 2) ^ (vc << 4)))        = v0[jj];
                *(bf16*)(row + (((vk0 + 32) * 2) ^ (vc << 4))) = v1[jj];
            }
        }
        __syncthreads();

        f32x4 s[2][4];
#pragma unroll
        for (int qf = 0; qf < 2; ++qf)
#pragma unroll
            for (int ktile = 0; ktile < 4; ++ktile) s[qf][ktile] = fzero;
#pragma unroll
        for (int ktile = 0; ktile < 4; ++ktile)
#pragma unroll
            for (int kk = 0; kk < 2; ++kk) {
                const int kr = ktile * 16 + lr;
                bf16x8 ak = *reinterpret_cast<const bf16x8*>(
                    Ksb + kr * 128 + ((kk * 64 + hi * 16) ^ ((kr & 7) << 4)));
#pragma unroll
                for (int qf = 0; qf < 2; ++qf)
                    s[qf][ktile] = __builtin_amdgcn_mfma_f32_16x16x32_bf16(
                        ak, aq[qf][kk], s[qf][ktile], 0, 0, 0);
            }

#pragma unroll
        for (int qf = 0; qf < 2; ++qf) {
            const int qglob = qbase + wv * 32 + qf * 16 + lr;
#pragma unroll
            for (int ktile = 0; ktile < 4; ++ktile) {
                const int kg0 = kt * 64 + ktile * 16 + hi * 4;
#pragma unroll
                for (int r = 0; r < 4; ++r) {
                    const float sv = s[qf][ktile][r] * SC;
                    s[qf][ktile][r] = (kg0 + r <= qglob) ? sv : -__builtin_inff();
                }
            }
        }

#pragma unroll
        for (int qf = 0; qf < 2; ++qf) {
            float tm = s[qf][0][0];
#pragma unroll
            for (int ktile = 0; ktile < 4; ++ktile)
#pragma unroll
                for (int r = 0; r < 4; ++r) tm = fmaxf(tm, s[qf][ktile][r]);
            tm = fmaxf(tm, __shfl_xor(tm, 16));
            tm = fmaxf(tm, __shfl_xor(tm, 32));

            const float mn = fmaxf(m_r[qf], tm);
            const float sc = __builtin_amdgcn_exp2f(m_r[qf] - mn);
            m_r[qf] = mn;

            float ts = 0.f;
#pragma unroll
            for (int ktile = 0; ktile < 4; ++ktile)
#pragma unroll
                for (int r = 0; r < 4; ++r) {
                    const float p = __builtin_amdgcn_exp2f(s[qf][ktile][r] - mn);
                    s[qf][ktile][r] = p;
                    ts += p;
                }
            ts += __shfl_xor(ts, 16);
            ts += __shfl_xor(ts, 32);
            l_r[qf] = l_r[qf] * sc + ts;

            float scb[4];
#pragma unroll
            for (int r = 0; r < 4; ++r) scb[r] = __shfl(sc, hi * 4 + r);
#pragma unroll
            for (int n = 0; n < 4; ++n)
#pragma unroll
                for (int r = 0; r < 4; ++r) oacc[qf][n][r] *= scb[r];

            const int q = qf * 16 + lr;
#pragma unroll
            for (int ktile = 0; ktile < 4; ++ktile) {
                bf16x4 p4;
#pragma unroll
                for (int r = 0; r < 4; ++r) p4[r] = (bf16)s[qf][ktile][r];
                *(bf16x4*)(Pb + q * 128 + ((ktile * 32 + hi * 8) ^ ((q & 7) << 4))) = p4;
            }
        }

#pragma unroll
        for (int kk = 0; kk < 2; ++kk) {
            bf16x8 ap[2];
#pragma unroll
            for (int qf = 0; qf < 2; ++qf) {
                const int q = qf * 16 + lr;
                ap[qf] = *reinterpret_cast<const bf16x8*>(
                    Pb + q * 128 + ((kk * 64 + hi * 16) ^ ((q & 7) << 4)));
            }
#pragma unroll
            for (int n = 0; n < 4; ++n) {
                const int d = n * 16 + lr;
                bf16x8 bv = *reinterpret_cast<const bf16x8*>(
                    Vtb + d * 128 + ((kk * 64 + hi * 16) ^ (((d >> 3) & 7) << 4)));
#pragma unroll
                for (int qf = 0; qf < 2; ++qf)
                    oacc[qf][n] = __builtin_amdgcn_mfma_f32_16x16x32_bf16(
                        ap[qf], bv, oacc[qf][n], 0, 0, 0);
            }
        }
    }

#pragma unroll
    for (int qf = 0; qf < 2; ++qf) {
        const float linv = 1.f / l_r[qf];
        float li[4];
#pragma unroll
        for (int r = 0; r < 4; ++r) li[r] = __shfl(linv, hi * 4 + r);
        bf16* og = o + (tokbase + qbase + wv * 32 + qf * 16) * (size_t)EMB + h * 64;
#pragma unroll
        for (int n = 0; n < 4; ++n)
#pragma unroll
            for (int r = 0; r < 4; ++r)
                og[(hi * 4 + r) * (size_t)EMB + n * 16 + lr] =
                    (bf16)(oacc[qf][n][r] * li[r]);
    }
}

// ---------------- launcher ----------------
extern "C" void kernel_launch(void* const* d_in, const int* in_sizes, int n_in,
                              void* d_out, int out_size, void* d_ws, size_t ws_size,
                              hipStream_t stream) {
    const float* x     = (const float*)d_in[0];
    const float* qkv_w = (const float*)d_in[1];
    const float* qkv_b = (const float*)d_in[2];
    const float* out_w = (const float*)d_in[3];
    const float* out_b = (const float*)d_in[4];
    float* out = (float*)d_out;

    // workspace layout (needs ~88 MB)
    char* ws = (char*)d_ws;
    bf16* x_bf    = (bf16*)(ws);                                  // 16 MB
    bf16* qkvw_bf = (bf16*)(ws + 16777216);                       //  6 MB
    bf16* outw_bf = (bf16*)(ws + 23068672);                       //  2 MB
    bf16* qkv_bf  = (bf16*)(ws + 25165824);                       // 48 MB
    bf16* o_bf    = (bf16*)(ws + 75497472);                       // 16 MB

    cvt_f32_bf16<<<8192, 256, 0, stream>>>(x,     x_bf,    NTOK * EMB);
    cvt_f32_bf16<<<3072, 256, 0, stream>>>(qkv_w, qkvw_bf, QKVF * EMB);
    cvt_f32_bf16<<<1024, 256, 0, stream>>>(out_w, outw_bf, EMB * EMB);

    // QKV projection: [8192,1024] x [3072,1024]^T -> bf16 [8192,3072]
    gemm_bt8<4, true><<<(QKVF / 256) * (NTOK / 256), 512, 0, stream>>>(
        x_bf, qkvw_bf, qkv_b, qkv_bf, NTOK, QKVF, EMB);

    // causal attention -> bf16 [8192,1024]
    attn_kernel<<<4 * 16 * (SEQ / 128), 256, 0, stream>>>(qkv_bf, o_bf);

    // output projection: [8192,1024] x [1024,1024]^T -> f32 d_out (BN=128, 256 blocks)
    gemm_bt8<2, false><<<(EMB / 128) * (NTOK / 256), 512, 0, stream>>>(
        o_bf, outw_bf, out_b, out, NTOK, EMB, EMB);
}